// Round 5
// baseline (956.105 us; speedup 1.0000x reference)
//
#include <hip/hip_runtime.h>
#include <hip/hip_bf16.h>
#include <hip/hip_cooperative_groups.h>
#include <stdint.h>

namespace cg = cooperative_groups;

// ---------------------------------------------------------------------------
// Supermask MLP (all fp32 I/O): global top-50% mask over score pool
// [sW1, sb1, sW2, sb2, sW3, sb3] applied to [W1, b1, W2, b2, W3, b3],
// then 3 GEMMs (bf16 MFMA, fp32 accumulate).
// R9: entire masking pipeline fused into ONE cooperative kernel
// (hist -> reduce -> select -> mask/cvt/zero -> finalize, grid.sync between
// phases; 11 dispatches -> 4 total). GEMMs keep the R8 2-phase template but
// the XCD swizzle is REVERTED (it tripled FETCH_SIZE: natural round-robin
// dispatch already gives each XCD a 4MB B-column working set = L2 size).
// ---------------------------------------------------------------------------

typedef __bf16 bf16_t;
typedef __bf16 bf16x4 __attribute__((ext_vector_type(4)));
typedef __bf16 bf16x8 __attribute__((ext_vector_type(8)));
typedef float  f32x4  __attribute__((ext_vector_type(4)));

using gvoid = const __attribute__((address_space(1))) void;
using svoid = __attribute__((address_space(3))) void;

#define O1 4194304L
#define O2 4198400L
#define O3 20975616L
#define O4 20979712L
#define O5 25174016L
#define N_TOT 25175040L
#define J_RANK 12587520u
#define CAND_CAP 4096

#define FUSED_BLOCKS 1024

// ws layout (bytes)
#define WS_HIST 0u
#define WS_RES  32768u
#define WS_CNT  32784u
#define WS_CAND 32800u
// fast path
#define WS_W1B  131072u
#define WS_B1F  8519680u
#define WS_W2B  8536064u
#define WS_B2F  42090496u
#define WS_W3B  42106880u
#define WS_B3F  50495488u
#define WS_H1F  50511872u
#define WS_H2F  58900480u
#define WS_FAST_END 67289088ull
// fallback path
#define WS_H1   131072u
#define WS_H2   8519680u

// LDS bank-conflict swizzle: physical 8-elt chunk for (row, logical chunk)
#define SWZ(row, chunk) ((((chunk) + ((row) >> 1)) & 3))

// monotone fp32-bits -> 32-bit key (ascending key == ascending float)
__device__ __forceinline__ unsigned int mono32(float f) {
    unsigned int u = __float_as_uint(f);
    return (u & 0x80000000u) ? ~u : (u | 0x80000000u);
}

__global__ __launch_bounds__(256) void zero_kernel(unsigned int* p, int n) {
    int i = blockIdx.x * 256 + threadIdx.x;
    if (i < n) p[i] = 0u;
}

__device__ __forceinline__ void seg_lookup(long e,
    const float* s0, const float* s1, const float* s2,
    const float* s3, const float* s4, const float* s5,
    const float** sp, long* off) {
    if (e < O1)      { *sp = s0; *off = e; }
    else if (e < O2) { *sp = s1; *off = e - O1; }
    else if (e < O3) { *sp = s2; *off = e - O2; }
    else if (e < O4) { *sp = s3; *off = e - O3; }
    else if (e < O5) { *sp = s4; *off = e - O4; }
    else             { *sp = s5; *off = e - O5; }
}

// ---------------------------------------------------------------------------
// Fused masking pipeline (cooperative, grid = FUSED_BLOCKS x 256).
// LDS (32 KB) reused: phase A = per-block histogram; phase E = candidate buf.
// hb (FUSED_BLOCKS x 8192 u32 = 32 MB) lives in the W2B region, which phase D
// overwrites only AFTER phase B consumed it (grid.sync separated).
// ---------------------------------------------------------------------------
struct FusedArgs {
    const float *s0, *s1, *s2, *s3, *s4, *s5;
    const float *w0, *w1, *w2, *w3, *w4, *w5;
    bf16_t* W1b; float* b1f; bf16_t* W2b; float* b2f; bf16_t* W3b; float* b3f;
    unsigned int* hb;
    unsigned int* hist;
    unsigned int* res;
    unsigned int* cnt;
    unsigned long long* cand;
    const float* x;
    bf16_t* xb;
    float* OUT;
};

__global__ __launch_bounds__(256, 4) void fused_mask(FusedArgs a) {
    cg::grid_group grid = cg::this_grid();
    __shared__ __align__(16) unsigned char shraw[32768];
    const int tid = threadIdx.x;
    const int bid = blockIdx.x;
    const int nblk = gridDim.x;                       // FUSED_BLOCKS
    const long gtid = (long)bid * 256 + tid;
    const long nthr = (long)nblk * 256;
    const long ng = N_TOT / 4;

    // ---- phase A: per-block LDS histogram -> private slice of hb ----
    unsigned int* lh = (unsigned int*)shraw;
    for (int i = tid; i < 8192; i += 256) lh[i] = 0u;
    if (gtid == 0) *a.cnt = 0u;
    __syncthreads();
    for (long g = gtid; g < ng; g += nthr) {
        long e = g * 4;
        const float* sp; long o;
        seg_lookup(e, a.s0, a.s1, a.s2, a.s3, a.s4, a.s5, &sp, &o);
        float4 v = *(const float4*)(sp + o);
        atomicAdd(&lh[mono32(v.x) >> 19], 1u);
        atomicAdd(&lh[mono32(v.y) >> 19], 1u);
        atomicAdd(&lh[mono32(v.z) >> 19], 1u);
        atomicAdd(&lh[mono32(v.w) >> 19], 1u);
    }
    __syncthreads();
    {
        unsigned int* dst = a.hb + (size_t)bid * 8192;
        for (int i = tid; i < 8192; i += 256) dst[i] = lh[i];
    }
    grid.sync();

    // ---- phase B: reduce slices (blocks 0..31; coalesced across threads) ----
    if (bid < 32) {
        int b = bid * 256 + tid;                      // 0..8191
        unsigned int s = 0;
        for (int blk = 0; blk < nblk; ++blk)
            s += a.hb[(size_t)blk * 8192 + b];
        a.hist[b] = s;
    }
    grid.sync();

    // ---- phase C: select threshold bucket (block 0) ----
    if (bid == 0) {
        unsigned int* part = (unsigned int*)shraw;    // reuse LDS
        unsigned int s = 0;
        for (int b = tid * 32; b < tid * 32 + 32; ++b) s += a.hist[b];
        part[tid] = s;
        __syncthreads();
        if (tid == 0) {
            unsigned int acc = 0;
            for (int i = 0; i < 256; ++i) { unsigned int v = part[i]; part[i] = acc; acc += v; }
        }
        __syncthreads();
        unsigned int acc = part[tid];
        for (int b = tid * 32; b < tid * 32 + 32; ++b) {
            unsigned int h = a.hist[b];
            if (acc <= J_RANK && J_RANK < acc + h) {
                a.res[0] = (unsigned int)b;
                a.res[1] = acc;
                a.res[2] = J_RANK - acc;   // # bucket members to DROP
            }
            acc += h;
        }
    }
    grid.sync();

    // ---- phase D: zero OUT + cvt x->bf16 + mask apply ----
    // OUT: 1,048,576 floats = nthr float4 stores (exact).
    *(float4*)(a.OUT + gtid * 4) = make_float4(0.f, 0.f, 0.f, 0.f);
    if (gtid < 131072) {
        const float4 p = *(const float4*)(a.x + gtid * 8);
        const float4 q = *(const float4*)(a.x + gtid * 8 + 4);
        bf16x8 r;
        r[0] = (__bf16)p.x; r[1] = (__bf16)p.y; r[2] = (__bf16)p.z; r[3] = (__bf16)p.w;
        r[4] = (__bf16)q.x; r[5] = (__bf16)q.y; r[6] = (__bf16)q.z; r[7] = (__bf16)q.w;
        *(bf16x8*)(a.xb + gtid * 8) = r;
    }
    {
        const unsigned int C = a.res[0];
        for (long g = gtid; g < ng; g += nthr) {
            long e = g * 4;
            const float* sp; long o;
            seg_lookup(e, a.s0, a.s1, a.s2, a.s3, a.s4, a.s5, &sp, &o);
            const float* wp;
            if (e < O1)      wp = a.w0;
            else if (e < O2) wp = a.w1;
            else if (e < O3) wp = a.w2;
            else if (e < O4) wp = a.w3;
            else if (e < O5) wp = a.w4;
            else             wp = a.w5;
            float4 sv = *(const float4*)(sp + o);
            float4 wv = *(const float4*)(wp + o);
#define PROC(comp, ci)                                                         \
            { unsigned int key = mono32(sv.comp); unsigned int kb = key >> 19; \
              if (kb < C) wv.comp = 0.f;                                       \
              else if (kb == C) {                                              \
                  unsigned int slot = atomicAdd(a.cnt, 1u);                    \
                  if (slot < CAND_CAP)                                         \
                      a.cand[slot] = (((unsigned long long)key) << 32) |       \
                                     (unsigned long long)(unsigned int)(e + ci);\
              } }
            PROC(x, 0) PROC(y, 1) PROC(z, 2) PROC(w, 3)
#undef PROC
            if (e < O1) {
                bf16x4 b; b[0]=(__bf16)wv.x; b[1]=(__bf16)wv.y; b[2]=(__bf16)wv.z; b[3]=(__bf16)wv.w;
                *(bf16x4*)(a.W1b + o) = b;
            } else if (e < O2) {
                *(float4*)(a.b1f + o) = wv;
            } else if (e < O3) {
                bf16x4 b; b[0]=(__bf16)wv.x; b[1]=(__bf16)wv.y; b[2]=(__bf16)wv.z; b[3]=(__bf16)wv.w;
                *(bf16x4*)(a.W2b + o) = b;
            } else if (e < O4) {
                *(float4*)(a.b2f + o) = wv;
            } else if (e < O5) {
                bf16x4 b; b[0]=(__bf16)wv.x; b[1]=(__bf16)wv.y; b[2]=(__bf16)wv.z; b[3]=(__bf16)wv.w;
                *(bf16x4*)(a.W3b + o) = b;
            } else {
                *(float4*)(a.b3f + o) = wv;
            }
        }
    }
    grid.sync();

    // ---- phase E: exact tie-break inside threshold bucket (block 0) ----
    if (bid == 0) {
        unsigned long long* buf = (unsigned long long*)shraw;  // reuse LDS
        unsigned int cnt = *a.cnt; if (cnt > CAND_CAP) cnt = CAND_CAP;
        unsigned int need = a.res[2]; if (need > cnt) need = cnt;
        for (int i = tid; i < (int)cnt; i += 256) buf[i] = a.cand[i];
        __syncthreads();
        for (int i = tid; i < (int)cnt; i += 256) {
            unsigned long long me = buf[i];
            unsigned int rank = 0;
            for (unsigned int j = 0; j < cnt; ++j) rank += (buf[j] < me);
            if (rank < need) {
                long idx = (long)(unsigned int)(me & 0xFFFFFFFFu);
                if (idx < O1)      a.W1b[idx] = (__bf16)0.f;
                else if (idx < O2) a.b1f[idx - O1] = 0.f;
                else if (idx < O3) a.W2b[idx - O2] = (__bf16)0.f;
                else if (idx < O4) a.b2f[idx - O3] = 0.f;
                else if (idx < O5) a.W3b[idx - O4] = (__bf16)0.f;
                else               a.b3f[idx - O5] = 0.f;
            }
        }
    }
}

// ---- fallback path kernels (in-place fp32 masking, atomic hist) ----
__global__ __launch_bounds__(256) void hist_atomic_kernel(
    const float* s0, const float* s1, const float* s2,
    const float* s3, const float* s4, const float* s5,
    unsigned int* hist) {
    __shared__ unsigned int lh[8192];
    for (int i = threadIdx.x; i < 8192; i += 256) lh[i] = 0u;
    __syncthreads();
    const long ng = N_TOT / 4;
    for (long g = (long)blockIdx.x * 256 + threadIdx.x; g < ng;
         g += (long)gridDim.x * 256) {
        long e = g * 4;
        const float* sp; long o;
        seg_lookup(e, s0, s1, s2, s3, s4, s5, &sp, &o);
        float4 v = *(const float4*)(sp + o);
        atomicAdd(&lh[mono32(v.x) >> 19], 1u);
        atomicAdd(&lh[mono32(v.y) >> 19], 1u);
        atomicAdd(&lh[mono32(v.z) >> 19], 1u);
        atomicAdd(&lh[mono32(v.w) >> 19], 1u);
    }
    __syncthreads();
    for (int i = threadIdx.x; i < 8192; i += 256) {
        unsigned int c = lh[i];
        if (c) atomicAdd(&hist[i], c);
    }
}

__global__ __launch_bounds__(256) void select_kernel(const unsigned int* hist,
                                                     unsigned int* res) {
    __shared__ unsigned int part[256];
    int tid = threadIdx.x;
    unsigned int s = 0;
    for (int b = tid * 32; b < tid * 32 + 32; ++b) s += hist[b];
    part[tid] = s;
    __syncthreads();
    if (tid == 0) {
        unsigned int acc = 0;
        for (int i = 0; i < 256; ++i) { unsigned int v = part[i]; part[i] = acc; acc += v; }
    }
    __syncthreads();
    unsigned int acc = part[tid];
    for (int b = tid * 32; b < tid * 32 + 32; ++b) {
        unsigned int h = hist[b];
        if (acc <= J_RANK && J_RANK < acc + h) {
            res[0] = (unsigned int)b;
            res[1] = acc;
            res[2] = J_RANK - acc;
        }
        acc += h;
    }
}

__global__ __launch_bounds__(256) void mask_apply_kernel(
    const float* s0, const float* s1, const float* s2,
    const float* s3, const float* s4, const float* s5,
    float* w0, float* w1, float* w2, float* w3, float* w4, float* w5,
    const unsigned int* res, unsigned int* cand_cnt, unsigned long long* cand) {
    const unsigned int C = res[0];
    const long ng = N_TOT / 4;
    for (long g = (long)blockIdx.x * 256 + threadIdx.x; g < ng;
         g += (long)gridDim.x * 256) {
        long e = g * 4;
        const float* sp; long o;
        seg_lookup(e, s0, s1, s2, s3, s4, s5, &sp, &o);
        float* wp;
        if (e < O1)      wp = w0;
        else if (e < O2) wp = w1;
        else if (e < O3) wp = w2;
        else if (e < O4) wp = w3;
        else if (e < O5) wp = w4;
        else             wp = w5;
        float4 sv = *(const float4*)(sp + o);
        float4 wv = *(float4*)(wp + o);
#define PROC(comp, ci)                                                         \
        { unsigned int key = mono32(sv.comp); unsigned int kb = key >> 19;     \
          if (kb < C) wv.comp = 0.f;                                           \
          else if (kb == C) {                                                  \
              unsigned int slot = atomicAdd(cand_cnt, 1u);                     \
              if (slot < CAND_CAP)                                             \
                  cand[slot] = (((unsigned long long)key) << 32) |             \
                               (unsigned long long)(unsigned int)(e + ci);     \
          } }
        PROC(x, 0) PROC(y, 1) PROC(z, 2) PROC(w, 3)
#undef PROC
        *(float4*)(wp + o) = wv;
    }
}

__global__ __launch_bounds__(256) void finalize_kernel(
    const unsigned int* res, const unsigned int* cand_cnt,
    const unsigned long long* cand,
    float* w0, float* w1, float* w2, float* w3, float* w4, float* w5) {
    __shared__ unsigned long long buf[CAND_CAP];
    int tid = threadIdx.x;
    unsigned int cnt = *cand_cnt; if (cnt > CAND_CAP) cnt = CAND_CAP;
    unsigned int need = res[2];   if (need > cnt) need = cnt;
    for (int i = tid; i < (int)cnt; i += 256) buf[i] = cand[i];
    __syncthreads();
    for (int i = tid; i < (int)cnt; i += 256) {
        unsigned long long me = buf[i];
        unsigned int rank = 0;
        for (unsigned int j = 0; j < cnt; ++j) rank += (buf[j] < me);
        if (rank < need) {
            long idx = (long)(unsigned int)(me & 0xFFFFFFFFu);
            if (idx < O1)      w0[idx] = 0.f;
            else if (idx < O2) w1[idx - O1] = 0.f;
            else if (idx < O3) w2[idx - O2] = 0.f;
            else if (idx < O4) w3[idx - O3] = 0.f;
            else if (idx < O5) w4[idx - O4] = 0.f;
            else               w5[idx - O5] = 0.f;
        }
    }
}

// ---------------------------------------------------------------------------
// GEMM helpers
// ---------------------------------------------------------------------------
__device__ __forceinline__ bf16x8 load8(const float* p) {
    float4 a = *(const float4*)p;
    float4 b = *(const float4*)(p + 4);
    bf16x8 r;
    r[0] = (__bf16)a.x; r[1] = (__bf16)a.y; r[2] = (__bf16)a.z; r[3] = (__bf16)a.w;
    r[4] = (__bf16)b.x; r[5] = (__bf16)b.y; r[6] = (__bf16)b.z; r[7] = (__bf16)b.w;
    return r;
}
__device__ __forceinline__ bf16x8 load8(const bf16_t* p) {
    return *(const bf16x8*)p;
}

// Fallback GEMM (VGPR-staged, 2 barriers/step).
template <int BM, int BN, bool RELU, typename TA, typename TB, typename TC>
__global__ __launch_bounds__(256) void gemm_bt(
    const TA* __restrict__ A, const TB* __restrict__ B,
    const float* __restrict__ bias, TC* __restrict__ C,
    int M, int N, int K) {
    constexpr int BK = 32;
    constexpr int WM = BM / 2, WN = BN / 2;
    constexpr int TM = WM / 16, TN = WN / 16;
    constexpr int CA = (BM * BK) / 8;
    constexpr int CB = (BN * BK) / 8;
    __shared__ __align__(16) bf16_t As[BM * BK];
    __shared__ __align__(16) bf16_t Bs[BN * BK];

    const int tid = threadIdx.x;
    const int w = tid >> 6, lane = tid & 63;
    const int quad = lane >> 4, l16 = lane & 15;
    const int wm = (w >> 1) * WM, wn = (w & 1) * WN;
    const int rowBase = blockIdx.y * BM;
    const int colBase = blockIdx.x * BN;

    f32x4 acc[TM][TN] = {};

    const TA* Ab = A + (size_t)rowBase * K;
    const TB* Bb = B + (size_t)colBase * K;

    for (int k0 = 0; k0 < K; k0 += BK) {
        __syncthreads();
#pragma unroll
        for (int c0 = 0; c0 < CA; c0 += 256) {
            int c = c0 + tid;
            int row = c >> 2, kc = c & 3;
            *(bf16x8*)&As[row * BK + SWZ(row, kc) * 8] =
                load8(Ab + (size_t)row * K + k0 + kc * 8);
        }
#pragma unroll
        for (int c0 = 0; c0 < CB; c0 += 256) {
            int c = c0 + tid;
            int row = c >> 2, kc = c & 3;
            *(bf16x8*)&Bs[row * BK + SWZ(row, kc) * 8] =
                load8(Bb + (size_t)row * K + k0 + kc * 8);
        }
        __syncthreads();
        bf16x8 af[TM], bfr[TN];
#pragma unroll
        for (int i = 0; i < TM; ++i) {
            int r = wm + i * 16 + l16;
            af[i] = *(const bf16x8*)&As[r * BK + SWZ(r, quad) * 8];
        }
#pragma unroll
        for (int j = 0; j < TN; ++j) {
            int r = wn + j * 16 + l16;
            bfr[j] = *(const bf16x8*)&Bs[r * BK + SWZ(r, quad) * 8];
        }
#pragma unroll
        for (int i = 0; i < TM; ++i)
#pragma unroll
            for (int j = 0; j < TN; ++j)
                acc[i][j] = __builtin_amdgcn_mfma_f32_16x16x32_bf16(
                    af[i], bfr[j], acc[i][j], 0, 0, 0);
    }

#pragma unroll
    for (int i = 0; i < TM; ++i) {
#pragma unroll
        for (int j = 0; j < TN; ++j) {
            int col = colBase + wn + j * 16 + l16;
            float bv = bias[col];
#pragma unroll
            for (int r = 0; r < 4; ++r) {
                int rowg = rowBase + wm + i * 16 + quad * 4 + r;
                float v = acc[i][j][r] + bv;
                if (RELU) v = v > 0.f ? v : 0.f;
                if constexpr (sizeof(TC) == 4)
                    C[(size_t)rowg * N + col] = v;
                else
                    C[(size_t)rowg * N + col] = (bf16_t)v;
            }
        }
    }
}

// ---------------------------------------------------------------------------
// 2-phase GEMM (fast path): C[M,N] = act( A[M,K] @ B[N,K]^T + bias[N] ).
// A, B bf16. 64x128 tile, 4 waves (2x2), 32x64 per-wave. Two LDS buffers;
// per K-step: { stage(next buf) ; ds_read+MFMA(cur) ; __syncthreads }.
// NO XCD remap: natural round-robin dispatch puts bx == xcd (mod 8) blocks
// on each XCD -> per-XCD B working set ~4MB = L2 size (R4 measured: a
// chunked remap tripled FETCH_SIZE).
// SPLITK>1: fp32 atomicAdd into pre-zeroed C, bias added by z==0 only.
// ---------------------------------------------------------------------------
template <bool RELU, int SPLITK, typename TC>
__global__ __launch_bounds__(256) void gemm2ph(
    const bf16_t* __restrict__ A, const bf16_t* __restrict__ B,
    const float* __restrict__ bias, TC* __restrict__ C,
    int M, int N, int K) {
    constexpr int BM = 64, BN = 128, BK = 32;
    constexpr int TM = 2, TN = 4;
    constexpr int CA = (BM * BK) / 8;   // 256 chunks: 1/thread
    constexpr int CB = (BN * BK) / 8;   // 512 chunks: 2/thread
    static_assert(CA == 256 && CB == 512, "staging assumes 3 loads/thread/step");
    __shared__ __align__(16) bf16_t As[2][BM * BK];
    __shared__ __align__(16) bf16_t Bs[2][BN * BK];

    const int tid = threadIdx.x;
    const int w = tid >> 6, lane = tid & 63;
    const int quad = lane >> 4, l16 = lane & 15;
    const int wm = (w >> 1) * 32, wn = (w & 1) * 64;

    const int rowBase = blockIdx.y * BM;
    const int colBase = blockIdx.x * BN;

    f32x4 acc[TM][TN] = {};

    const bf16_t* Ab = A + (size_t)rowBase * K;
    const bf16_t* Bb = B + (size_t)colBase * K;

    const int kPart = K / SPLITK;
    const int kBeg = (SPLITK > 1) ? (int)blockIdx.z * kPart : 0;
    const int nt = kPart / BK;

    // Per-thread staging addresses. Chunk c: row=c>>2, phys=c&3; global src
    // uses logical chunk lc = inverse-SWZ so a LINEAR LDS write at c*8
    // reproduces the swizzled layout the ds_read side expects (m104/m173).
    const int rA = tid >> 2;
    const int lA = ((tid & 3) - (rA >> 1)) & 3;
    const int cB1 = tid + 256;
    const int rB1 = cB1 >> 2;
    const int lB1 = ((cB1 & 3) - (rB1 >> 1)) & 3;
    const bf16_t* aSrc  = Ab + (size_t)rA * K + lA * 8;
    const bf16_t* bSrc0 = Bb + (size_t)rA * K + lA * 8;
    const bf16_t* bSrc1 = Bb + (size_t)rB1 * K + lB1 * 8;

    auto stage = [&](int buf, int k0) {
        __builtin_amdgcn_global_load_lds((gvoid*)(aSrc + k0),
            (svoid*)(As[buf] + (size_t)tid * 8), 16, 0, 0);
        __builtin_amdgcn_global_load_lds((gvoid*)(bSrc0 + k0),
            (svoid*)(Bs[buf] + (size_t)tid * 8), 16, 0, 0);
        __builtin_amdgcn_global_load_lds((gvoid*)(bSrc1 + k0),
            (svoid*)(Bs[buf] + (size_t)cB1 * 8), 16, 0, 0);
    };
    auto compute = [&](int buf) {
        bf16x8 af[TM], bfr[TN];
#pragma unroll
        for (int i = 0; i < TM; ++i) {
            int r = wm + i * 16 + l16;
            af[i] = *(const bf16x8*)&As[buf][r * BK + SWZ(r, quad) * 8];
        }
#pragma unroll
        for (int j = 0; j < TN; ++j) {
            int r = wn + j * 16 + l16;
            bfr[j] = *(const bf16x8*)&Bs[buf][r * BK + SWZ(r, quad) * 8];
        }
#pragma unroll
        for (int i = 0; i < TM; ++i)
#pragma unroll
            for (int j = 0; j < TN; ++j)
                acc[i][j] = __builtin_amdgcn_mfma_f32_16x16x32_bf16(
                    af[i], bfr[j], acc[i][j], 0, 0, 0);
    };

    stage(0, kBeg);
    __syncthreads();                       // drains vmcnt(0): buf0 ready
    for (int t = 0; t < nt - 1; ++t) {
        stage((t + 1) & 1, kBeg + (t + 1) * BK);  // overlaps compute below
        compute(t & 1);
        __syncthreads();                   // drain + barrier: next buf ready
    }
    compute((nt - 1) & 1);

#pragma unroll
    for (int i = 0; i < TM; ++i) {
#pragma unroll
        for (int j = 0; j < TN; ++j) {
            int col = colBase + wn + j * 16 + l16;
            float bv = (SPLITK == 1 || blockIdx.z == 0) ? bias[col] : 0.f;
#pragma unroll
            for (int r = 0; r < 4; ++r) {
                int rowg = rowBase + wm + i * 16 + quad * 4 + r;
                float v = acc[i][j][r] + bv;
                if constexpr (SPLITK == 1) {
                    if (RELU) v = v > 0.f ? v : 0.f;
                    if constexpr (sizeof(TC) == 4)
                        C[(size_t)rowg * N + col] = v;
                    else
                        C[(size_t)rowg * N + col] = (bf16_t)v;
                } else {
                    atomicAdd((float*)&C[(size_t)rowg * N + col], v);
                }
            }
        }
    }
}

extern "C" void kernel_launch(void* const* d_in, const int* in_sizes, int n_in,
                              void* d_out, int out_size, void* d_ws, size_t ws_size,
                              hipStream_t stream) {
    const float* x  = (const float*)d_in[0];
    float* W1 = (float*)d_in[1];
    float* b1 = (float*)d_in[2];
    float* W2 = (float*)d_in[3];
    float* b2 = (float*)d_in[4];
    float* W3 = (float*)d_in[5];
    float* b3 = (float*)d_in[6];
    const float* s0 = (const float*)d_in[7];
    const float* s1 = (const float*)d_in[8];
    const float* s2 = (const float*)d_in[9];
    const float* s3 = (const float*)d_in[10];
    const float* s4 = (const float*)d_in[11];
    const float* s5 = (const float*)d_in[12];

    uint8_t* ws = (uint8_t*)d_ws;
    unsigned int* hist = (unsigned int*)(ws + WS_HIST);
    unsigned int* res  = (unsigned int*)(ws + WS_RES);
    unsigned int* cnt  = (unsigned int*)(ws + WS_CNT);
    unsigned long long* cand = (unsigned long long*)(ws + WS_CAND);
    float* OUT = (float*)d_out;

    if (ws_size >= WS_FAST_END) {
        bf16_t* W1b = (bf16_t*)(ws + WS_W1B);
        float*  b1f = (float*)(ws + WS_B1F);
        bf16_t* W2b = (bf16_t*)(ws + WS_W2B);
        float*  b2f = (float*)(ws + WS_B2F);
        bf16_t* W3b = (bf16_t*)(ws + WS_W3B);
        float*  b3f = (float*)(ws + WS_B3F);
        bf16_t* H1  = (bf16_t*)(ws + WS_H1F);
        bf16_t* H2  = (bf16_t*)(ws + WS_H2F);
        // hb scratch (1024 x 32KB = 32 MB) in the W2B region: consumed by
        // phase B before phase D overwrites it with W2b (grid.sync ordered).
        unsigned int* hb = (unsigned int*)(ws + WS_W2B);
        // xb parked in the H2 region: only read by GEMM1, which completes
        // before GEMM2 starts writing H2 (same stream).
        bf16_t* xb  = (bf16_t*)(ws + WS_H2F);

        FusedArgs fa;
        fa.s0 = s0; fa.s1 = s1; fa.s2 = s2; fa.s3 = s3; fa.s4 = s4; fa.s5 = s5;
        fa.w0 = W1; fa.w1 = b1; fa.w2 = W2; fa.w3 = b2; fa.w4 = W3; fa.w5 = b3;
        fa.W1b = W1b; fa.b1f = b1f; fa.W2b = W2b; fa.b2f = b2f;
        fa.W3b = W3b; fa.b3f = b3f;
        fa.hb = hb; fa.hist = hist; fa.res = res; fa.cnt = cnt; fa.cand = cand;
        fa.x = x; fa.xb = xb; fa.OUT = OUT;
        void* kargs[] = { (void*)&fa };
        hipLaunchCooperativeKernel((const void*)fused_mask,
                                   dim3(FUSED_BLOCKS), dim3(256),
                                   kargs, 0, stream);

        gemm2ph<true, 1, bf16_t>
            <<<dim3(32, 16), 256, 0, stream>>>(xb, W1b, b1f, H1, 1024, 4096, 1024);
        gemm2ph<true, 1, bf16_t>
            <<<dim3(32, 16), 256, 0, stream>>>(H1, W2b, b2f, H2, 1024, 4096, 4096);
        gemm2ph<false, 4, float>
            <<<dim3(8, 16, 4), 256, 0, stream>>>(H2, W3b, b3f, OUT, 1024, 1024, 4096);
    } else {
        bf16_t* H1 = (bf16_t*)(ws + WS_H1);
        bf16_t* H2 = (bf16_t*)(ws + WS_H2);
        zero_kernel<<<33, 256, 0, stream>>>((unsigned int*)ws, 8200);
        hist_atomic_kernel<<<1024, 256, 0, stream>>>(s0, s1, s2, s3, s4, s5, hist);
        select_kernel<<<1, 256, 0, stream>>>(hist, res);
        mask_apply_kernel<<<2048, 256, 0, stream>>>(s0, s1, s2, s3, s4, s5,
                                                    W1, b1, W2, b2, W3, b3,
                                                    res, cnt, cand);
        finalize_kernel<<<1, 256, 0, stream>>>(res, cnt, cand,
                                               W1, b1, W2, b2, W3, b3);
        gemm_bt<64, 128, true, float, float, bf16_t>
            <<<dim3(32, 16), 256, 0, stream>>>(x, W1, b1, H1, 1024, 4096, 1024);
        gemm_bt<64, 128, true, bf16_t, float, bf16_t>
            <<<dim3(32, 16), 256, 0, stream>>>(H1, W2, b2, H2, 1024, 4096, 4096);
        gemm_bt<64, 64, false, bf16_t, float, float>
            <<<dim3(16, 16), 256, 0, stream>>>(H2, W3, b3, OUT, 1024, 1024, 4096);
    }
}

// Round 6
// 377.955 us; speedup vs baseline: 2.5297x; 2.5297x over previous
//
#include <hip/hip_runtime.h>
#include <hip/hip_bf16.h>
#include <stdint.h>

// ---------------------------------------------------------------------------
// Supermask MLP (all fp32 I/O): global top-50% mask over score pool
// [sW1, sb1, sW2, sb2, sW3, sb3] applied to [W1, b1, W2, b2, W3, b3],
// then 3 GEMMs (bf16 MFMA, fp32 accumulate).
// R10: cooperative fusion REVERTED (measured 668us @ 390GB/s — grid.sync
// serialization). Separate dispatches, 8 launches total:
//   hist(512 slices) -> reduce(32) -> select(1, zeroes cnt) ->
//   mask_apply(2048, also zeroes OUT + converts x->bf16) -> finalize(1) ->
//   3x gemm2ph (BK=64: per-step compute ~550cyc covers HBM latency at the
//   one-barrier-per-step drain; SWZ8 swizzle, inverse-swizzled DMA source).
// ---------------------------------------------------------------------------

typedef __bf16 bf16_t;
typedef __bf16 bf16x4 __attribute__((ext_vector_type(4)));
typedef __bf16 bf16x8 __attribute__((ext_vector_type(8)));
typedef float  f32x4  __attribute__((ext_vector_type(4)));

using gvoid = const __attribute__((address_space(1))) void;
using svoid = __attribute__((address_space(3))) void;

#define O1 4194304L
#define O2 4198400L
#define O3 20975616L
#define O4 20979712L
#define O5 25174016L
#define N_TOT 25175040L
#define J_RANK 12587520u
#define CAND_CAP 4096

#define HIST_BLOCKS 512

// ws layout (bytes)
#define WS_HIST 0u
#define WS_RES  32768u
#define WS_CNT  32784u
#define WS_CAND 32800u
// fast path
#define WS_W1B  131072u
#define WS_B1F  8519680u
#define WS_W2B  8536064u
#define WS_B2F  42090496u
#define WS_W3B  42106880u
#define WS_B3F  50495488u
#define WS_H1F  50511872u
#define WS_H2F  58900480u
#define WS_FAST_END 67289088ull
// fallback path
#define WS_H1   131072u
#define WS_H2   8519680u

// BK=32 swizzle (fallback gemm_bt): physical 8-elt chunk for (row, chunk)
#define SWZ(row, chunk) ((((chunk) + ((row) >> 1)) & 3))
// BK=64 swizzle (gemm2ph): 8 chunks/row, rotate by row (2-way max per
// 16-lane phase on ds_read_b128; row stride 128B = full bank span)
#define SWZ8(row, chunk) ((((chunk) + (row)) & 7))

// monotone fp32-bits -> 32-bit key (ascending key == ascending float)
__device__ __forceinline__ unsigned int mono32(float f) {
    unsigned int u = __float_as_uint(f);
    return (u & 0x80000000u) ? ~u : (u | 0x80000000u);
}

__global__ __launch_bounds__(256) void zero_kernel(unsigned int* p, int n) {
    int i = blockIdx.x * 256 + threadIdx.x;
    if (i < n) p[i] = 0u;
}

__device__ __forceinline__ void seg_lookup(long e,
    const float* s0, const float* s1, const float* s2,
    const float* s3, const float* s4, const float* s5,
    const float** sp, long* off) {
    if (e < O1)      { *sp = s0; *off = e; }
    else if (e < O2) { *sp = s1; *off = e - O1; }
    else if (e < O3) { *sp = s2; *off = e - O2; }
    else if (e < O4) { *sp = s3; *off = e - O3; }
    else if (e < O5) { *sp = s4; *off = e - O4; }
    else             { *sp = s5; *off = e - O5; }
}

// Per-block local hist -> non-atomic store to private 32KB slice of hb.
__global__ __launch_bounds__(256) void hist_kernel(
    const float* s0, const float* s1, const float* s2,
    const float* s3, const float* s4, const float* s5,
    unsigned int* hb) {
    __shared__ unsigned int lh[8192];
    for (int i = threadIdx.x; i < 8192; i += 256) lh[i] = 0u;
    __syncthreads();
    const long ng = N_TOT / 4;
    for (long g = (long)blockIdx.x * 256 + threadIdx.x; g < ng;
         g += (long)gridDim.x * 256) {
        long e = g * 4;
        const float* sp; long o;
        seg_lookup(e, s0, s1, s2, s3, s4, s5, &sp, &o);
        float4 v = *(const float4*)(sp + o);
        atomicAdd(&lh[mono32(v.x) >> 19], 1u);
        atomicAdd(&lh[mono32(v.y) >> 19], 1u);
        atomicAdd(&lh[mono32(v.z) >> 19], 1u);
        atomicAdd(&lh[mono32(v.w) >> 19], 1u);
    }
    __syncthreads();
    unsigned int* dst = hb + (size_t)blockIdx.x * 8192;
    for (int i = threadIdx.x; i < 8192; i += 256) dst[i] = lh[i];
}

// hist[b] = sum over HIST_BLOCKS slices (coalesced across threads)
__global__ __launch_bounds__(256) void reduce_hist(const unsigned int* __restrict__ hb,
                                                   unsigned int* __restrict__ hist) {
    int b = blockIdx.x * 256 + threadIdx.x;   // 0..8191 (grid 32x256)
    unsigned int s = 0;
    for (int blk = 0; blk < HIST_BLOCKS; ++blk)
        s += hb[(size_t)blk * 8192 + b];
    hist[b] = s;
}

// select threshold bucket; also zeroes the candidate counter (pre-mask_apply)
__global__ __launch_bounds__(256) void select_kernel(const unsigned int* hist,
                                                     unsigned int* res,
                                                     unsigned int* cnt) {
    __shared__ unsigned int part[256];
    int tid = threadIdx.x;
    if (tid == 0) *cnt = 0u;
    unsigned int s = 0;
    for (int b = tid * 32; b < tid * 32 + 32; ++b) s += hist[b];
    part[tid] = s;
    __syncthreads();
    if (tid == 0) {
        unsigned int acc = 0;
        for (int i = 0; i < 256; ++i) { unsigned int v = part[i]; part[i] = acc; acc += v; }
    }
    __syncthreads();
    unsigned int acc = part[tid];
    for (int b = tid * 32; b < tid * 32 + 32; ++b) {
        unsigned int h = hist[b];
        if (acc <= J_RANK && J_RANK < acc + h) {
            res[0] = (unsigned int)b;
            res[1] = acc;
            res[2] = J_RANK - acc;   // # bucket members (lowest key,idx) to DROP
        }
        acc += h;
    }
}

// ---- fast path: read scores+weights fp32, write masked weights bf16 to ws;
// biases fp32 to ws. Also zeroes OUT (for GEMM3 split-K atomics) and
// converts x -> bf16 (xb). Collects threshold-bucket candidates.
__global__ __launch_bounds__(256) void mask_apply_fast(
    const float* s0, const float* s1, const float* s2,
    const float* s3, const float* s4, const float* s5,
    const float* w0, const float* w1, const float* w2,
    const float* w3, const float* w4, const float* w5,
    bf16_t* W1b, float* b1f, bf16_t* W2b, float* b2f, bf16_t* W3b, float* b3f,
    const unsigned int* res, unsigned int* cand_cnt, unsigned long long* cand,
    const float* xsrc, bf16_t* xb, float* OUT) {
    const long gtid = (long)blockIdx.x * 256 + threadIdx.x;
    // zero OUT: 1,048,576 floats = 262144 float4 stores
    if (gtid < 262144)
        *(float4*)(OUT + gtid * 4) = make_float4(0.f, 0.f, 0.f, 0.f);
    // cvt x -> bf16: 1,048,576 floats = 131072 x 8
    if (gtid < 131072) {
        const float4 p = *(const float4*)(xsrc + gtid * 8);
        const float4 q = *(const float4*)(xsrc + gtid * 8 + 4);
        bf16x8 r;
        r[0] = (__bf16)p.x; r[1] = (__bf16)p.y; r[2] = (__bf16)p.z; r[3] = (__bf16)p.w;
        r[4] = (__bf16)q.x; r[5] = (__bf16)q.y; r[6] = (__bf16)q.z; r[7] = (__bf16)q.w;
        *(bf16x8*)(xb + gtid * 8) = r;
    }
    const unsigned int C = res[0];
    const long ng = N_TOT / 4;
    for (long g = gtid; g < ng; g += (long)gridDim.x * 256) {
        long e = g * 4;
        const float* sp; long o;
        seg_lookup(e, s0, s1, s2, s3, s4, s5, &sp, &o);
        const float* wp;
        if (e < O1)      wp = w0;
        else if (e < O2) wp = w1;
        else if (e < O3) wp = w2;
        else if (e < O4) wp = w3;
        else if (e < O5) wp = w4;
        else             wp = w5;
        float4 sv = *(const float4*)(sp + o);
        float4 wv = *(const float4*)(wp + o);
#define PROC(comp, ci)                                                         \
        { unsigned int key = mono32(sv.comp); unsigned int kb = key >> 19;     \
          if (kb < C) wv.comp = 0.f;                                           \
          else if (kb == C) {                                                  \
              unsigned int slot = atomicAdd(cand_cnt, 1u);                     \
              if (slot < CAND_CAP)                                             \
                  cand[slot] = (((unsigned long long)key) << 32) |             \
                               (unsigned long long)(unsigned int)(e + ci);     \
          } }
        PROC(x, 0) PROC(y, 1) PROC(z, 2) PROC(w, 3)
#undef PROC
        if (e < O1) {
            bf16x4 b; b[0]=(__bf16)wv.x; b[1]=(__bf16)wv.y; b[2]=(__bf16)wv.z; b[3]=(__bf16)wv.w;
            *(bf16x4*)(W1b + o) = b;
        } else if (e < O2) {
            *(float4*)(b1f + o) = wv;
        } else if (e < O3) {
            bf16x4 b; b[0]=(__bf16)wv.x; b[1]=(__bf16)wv.y; b[2]=(__bf16)wv.z; b[3]=(__bf16)wv.w;
            *(bf16x4*)(W2b + o) = b;
        } else if (e < O4) {
            *(float4*)(b2f + o) = wv;
        } else if (e < O5) {
            bf16x4 b; b[0]=(__bf16)wv.x; b[1]=(__bf16)wv.y; b[2]=(__bf16)wv.z; b[3]=(__bf16)wv.w;
            *(bf16x4*)(W3b + o) = b;
        } else {
            *(float4*)(b3f + o) = wv;
        }
    }
}

__global__ __launch_bounds__(256) void finalize_fast(
    const unsigned int* res, const unsigned int* cand_cnt,
    const unsigned long long* cand,
    bf16_t* W1b, float* b1f, bf16_t* W2b, float* b2f, bf16_t* W3b, float* b3f) {
    __shared__ unsigned long long buf[CAND_CAP];
    int tid = threadIdx.x;
    unsigned int cnt = *cand_cnt; if (cnt > CAND_CAP) cnt = CAND_CAP;
    unsigned int need = res[2];   if (need > cnt) need = cnt;
    for (int i = tid; i < (int)cnt; i += 256) buf[i] = cand[i];
    __syncthreads();
    for (int i = tid; i < (int)cnt; i += 256) {
        unsigned long long me = buf[i];
        unsigned int rank = 0;
        for (unsigned int j = 0; j < cnt; ++j) rank += (buf[j] < me);
        if (rank < need) {
            long idx = (long)(unsigned int)(me & 0xFFFFFFFFu);
            if (idx < O1)      W1b[idx] = (__bf16)0.f;
            else if (idx < O2) b1f[idx - O1] = 0.f;
            else if (idx < O3) W2b[idx - O2] = (__bf16)0.f;
            else if (idx < O4) b2f[idx - O3] = 0.f;
            else if (idx < O5) W3b[idx - O4] = (__bf16)0.f;
            else               b3f[idx - O5] = 0.f;
        }
    }
}

// ---- fallback path kernels (in-place fp32 masking, atomic hist) ----
__global__ __launch_bounds__(256) void hist_atomic_kernel(
    const float* s0, const float* s1, const float* s2,
    const float* s3, const float* s4, const float* s5,
    unsigned int* hist) {
    __shared__ unsigned int lh[8192];
    for (int i = threadIdx.x; i < 8192; i += 256) lh[i] = 0u;
    __syncthreads();
    const long ng = N_TOT / 4;
    for (long g = (long)blockIdx.x * 256 + threadIdx.x; g < ng;
         g += (long)gridDim.x * 256) {
        long e = g * 4;
        const float* sp; long o;
        seg_lookup(e, s0, s1, s2, s3, s4, s5, &sp, &o);
        float4 v = *(const float4*)(sp + o);
        atomicAdd(&lh[mono32(v.x) >> 19], 1u);
        atomicAdd(&lh[mono32(v.y) >> 19], 1u);
        atomicAdd(&lh[mono32(v.z) >> 19], 1u);
        atomicAdd(&lh[mono32(v.w) >> 19], 1u);
    }
    __syncthreads();
    for (int i = threadIdx.x; i < 8192; i += 256) {
        unsigned int c = lh[i];
        if (c) atomicAdd(&hist[i], c);
    }
}

__global__ __launch_bounds__(256) void mask_apply_kernel(
    const float* s0, const float* s1, const float* s2,
    const float* s3, const float* s4, const float* s5,
    float* w0, float* w1, float* w2, float* w3, float* w4, float* w5,
    const unsigned int* res, unsigned int* cand_cnt, unsigned long long* cand) {
    const unsigned int C = res[0];
    const long ng = N_TOT / 4;
    for (long g = (long)blockIdx.x * 256 + threadIdx.x; g < ng;
         g += (long)gridDim.x * 256) {
        long e = g * 4;
        const float* sp; long o;
        seg_lookup(e, s0, s1, s2, s3, s4, s5, &sp, &o);
        float* wp;
        if (e < O1)      wp = w0;
        else if (e < O2) wp = w1;
        else if (e < O3) wp = w2;
        else if (e < O4) wp = w3;
        else if (e < O5) wp = w4;
        else             wp = w5;
        float4 sv = *(const float4*)(sp + o);
        float4 wv = *(float4*)(wp + o);
#define PROC(comp, ci)                                                         \
        { unsigned int key = mono32(sv.comp); unsigned int kb = key >> 19;     \
          if (kb < C) wv.comp = 0.f;                                           \
          else if (kb == C) {                                                  \
              unsigned int slot = atomicAdd(cand_cnt, 1u);                     \
              if (slot < CAND_CAP)                                             \
                  cand[slot] = (((unsigned long long)key) << 32) |             \
                               (unsigned long long)(unsigned int)(e + ci);     \
          } }
        PROC(x, 0) PROC(y, 1) PROC(z, 2) PROC(w, 3)
#undef PROC
        *(float4*)(wp + o) = wv;
    }
}

__global__ __launch_bounds__(256) void finalize_kernel(
    const unsigned int* res, const unsigned int* cand_cnt,
    const unsigned long long* cand,
    float* w0, float* w1, float* w2, float* w3, float* w4, float* w5) {
    __shared__ unsigned long long buf[CAND_CAP];
    int tid = threadIdx.x;
    unsigned int cnt = *cand_cnt; if (cnt > CAND_CAP) cnt = CAND_CAP;
    unsigned int need = res[2];   if (need > cnt) need = cnt;
    for (int i = tid; i < (int)cnt; i += 256) buf[i] = cand[i];
    __syncthreads();
    for (int i = tid; i < (int)cnt; i += 256) {
        unsigned long long me = buf[i];
        unsigned int rank = 0;
        for (unsigned int j = 0; j < cnt; ++j) rank += (buf[j] < me);
        if (rank < need) {
            long idx = (long)(unsigned int)(me & 0xFFFFFFFFu);
            if (idx < O1)      w0[idx] = 0.f;
            else if (idx < O2) w1[idx - O1] = 0.f;
            else if (idx < O3) w2[idx - O2] = 0.f;
            else if (idx < O4) w3[idx - O3] = 0.f;
            else if (idx < O5) w4[idx - O4] = 0.f;
            else               w5[idx - O5] = 0.f;
        }
    }
}

// ---------------------------------------------------------------------------
// GEMM helpers
// ---------------------------------------------------------------------------
__device__ __forceinline__ bf16x8 load8(const float* p) {
    float4 a = *(const float4*)p;
    float4 b = *(const float4*)(p + 4);
    bf16x8 r;
    r[0] = (__bf16)a.x; r[1] = (__bf16)a.y; r[2] = (__bf16)a.z; r[3] = (__bf16)a.w;
    r[4] = (__bf16)b.x; r[5] = (__bf16)b.y; r[6] = (__bf16)b.z; r[7] = (__bf16)b.w;
    return r;
}
__device__ __forceinline__ bf16x8 load8(const bf16_t* p) {
    return *(const bf16x8*)p;
}

// Fallback GEMM (VGPR-staged, 2 barriers/step, BK=32).
template <int BM, int BN, bool RELU, typename TA, typename TB, typename TC>
__global__ __launch_bounds__(256) void gemm_bt(
    const TA* __restrict__ A, const TB* __restrict__ B,
    const float* __restrict__ bias, TC* __restrict__ C,
    int M, int N, int K) {
    constexpr int BK = 32;
    constexpr int WM = BM / 2, WN = BN / 2;
    constexpr int TM = WM / 16, TN = WN / 16;
    constexpr int CA = (BM * BK) / 8;
    constexpr int CB = (BN * BK) / 8;
    __shared__ __align__(16) bf16_t As[BM * BK];
    __shared__ __align__(16) bf16_t Bs[BN * BK];

    const int tid = threadIdx.x;
    const int w = tid >> 6, lane = tid & 63;
    const int quad = lane >> 4, l16 = lane & 15;
    const int wm = (w >> 1) * WM, wn = (w & 1) * WN;
    const int rowBase = blockIdx.y * BM;
    const int colBase = blockIdx.x * BN;

    f32x4 acc[TM][TN] = {};

    const TA* Ab = A + (size_t)rowBase * K;
    const TB* Bb = B + (size_t)colBase * K;

    for (int k0 = 0; k0 < K; k0 += BK) {
        __syncthreads();
#pragma unroll
        for (int c0 = 0; c0 < CA; c0 += 256) {
            int c = c0 + tid;
            int row = c >> 2, kc = c & 3;
            *(bf16x8*)&As[row * BK + SWZ(row, kc) * 8] =
                load8(Ab + (size_t)row * K + k0 + kc * 8);
        }
#pragma unroll
        for (int c0 = 0; c0 < CB; c0 += 256) {
            int c = c0 + tid;
            int row = c >> 2, kc = c & 3;
            *(bf16x8*)&Bs[row * BK + SWZ(row, kc) * 8] =
                load8(Bb + (size_t)row * K + k0 + kc * 8);
        }
        __syncthreads();
        bf16x8 af[TM], bfr[TN];
#pragma unroll
        for (int i = 0; i < TM; ++i) {
            int r = wm + i * 16 + l16;
            af[i] = *(const bf16x8*)&As[r * BK + SWZ(r, quad) * 8];
        }
#pragma unroll
        for (int j = 0; j < TN; ++j) {
            int r = wn + j * 16 + l16;
            bfr[j] = *(const bf16x8*)&Bs[r * BK + SWZ(r, quad) * 8];
        }
#pragma unroll
        for (int i = 0; i < TM; ++i)
#pragma unroll
            for (int j = 0; j < TN; ++j)
                acc[i][j] = __builtin_amdgcn_mfma_f32_16x16x32_bf16(
                    af[i], bfr[j], acc[i][j], 0, 0, 0);
    }

#pragma unroll
    for (int i = 0; i < TM; ++i) {
#pragma unroll
        for (int j = 0; j < TN; ++j) {
            int col = colBase + wn + j * 16 + l16;
            float bv = bias[col];
#pragma unroll
            for (int r = 0; r < 4; ++r) {
                int rowg = rowBase + wm + i * 16 + quad * 4 + r;
                float v = acc[i][j][r] + bv;
                if (RELU) v = v > 0.f ? v : 0.f;
                if constexpr (sizeof(TC) == 4)
                    C[(size_t)rowg * N + col] = v;
                else
                    C[(size_t)rowg * N + col] = (bf16_t)v;
            }
        }
    }
}

// ---------------------------------------------------------------------------
// 2-phase GEMM, BK=64 (fast path): C[M,N] = act( A[M,K] @ B[N,K]^T + bias ).
// A, B bf16. 64x128 tile, 4 waves (2x2), 32x64 per-wave, 2 MFMA k-halves.
// Per K-step: { stage(next buf): 6x global_load_lds dwordx4 ; 12x ds_read +
// 16x MFMA (cur) ; __syncthreads }. Compute ~550cyc covers the staged loads'
// HBM latency before the barrier's vmcnt(0) drain; half the barriers of BK=32.
// LDS layout: row-major [row][64], 8-elt chunks swizzled SWZ8=(chunk+row)&7.
// Read conflicts: per 16-lane phase each 4-bank group gets 2 lanes = free.
// Staging: LINEAR LDS dest (chunk c -> byte c*8*2), global source uses
// lc=(phys-row)&7 (inverse SWZ8) per m104/m173.
// No XCD remap (R4: remap tripled FETCH_SIZE; natural round-robin is L2-opt).
// SPLITK>1: fp32 atomicAdd into pre-zeroed C, bias added by z==0 only.
// ---------------------------------------------------------------------------
template <bool RELU, int SPLITK, typename TC>
__global__ __launch_bounds__(256) void gemm2ph(
    const bf16_t* __restrict__ A, const bf16_t* __restrict__ B,
    const float* __restrict__ bias, TC* __restrict__ C,
    int M, int N, int K) {
    constexpr int BM = 64, BN = 128, BK = 64;
    constexpr int TM = 2, TN = 4;
    constexpr int CA = (BM * BK) / 8;   // 512 chunks: 2/thread
    constexpr int CB = (BN * BK) / 8;   // 1024 chunks: 4/thread
    static_assert(CA == 512 && CB == 1024, "staging assumes 6 loads/thread/step");
    __shared__ __align__(16) bf16_t As[2][BM * BK];   // 16 KB
    __shared__ __align__(16) bf16_t Bs[2][BN * BK];   // 32 KB

    const int tid = threadIdx.x;
    const int w = tid >> 6, lane = tid & 63;
    const int quad = lane >> 4, l16 = lane & 15;
    const int wm = (w >> 1) * 32, wn = (w & 1) * 64;

    const int rowBase = blockIdx.y * BM;
    const int colBase = blockIdx.x * BN;

    f32x4 acc[TM][TN] = {};

    const bf16_t* Ab = A + (size_t)rowBase * K;
    const bf16_t* Bb = B + (size_t)colBase * K;

    const int kPart = K / SPLITK;
    const int kBeg = (SPLITK > 1) ? (int)blockIdx.z * kPart : 0;
    const int nt = kPart / BK;

    // Staging addresses. Chunk c: row = c>>3, phys = c&7; logical chunk
    // lc = (phys - row) & 7 so a linear LDS write at c*8 elems lands the
    // data where SWZ8 reads expect it.
    const int rA0 = tid >> 3,          lA0 = ((tid & 3 * 2 + 1 & 0) + ((tid & 7) - rA0)) & 7;
    // (expression kept simple below; the line above is not used)
#define CHUNK_SRC(base, c) ((base) + (size_t)((c) >> 3) * K + ((((c) & 7) - ((c) >> 3)) & 7) * 8)
    const bf16_t* aS0 = CHUNK_SRC(Ab, tid);
    const bf16_t* aS1 = CHUNK_SRC(Ab, tid + 256);
    const bf16_t* bS0 = CHUNK_SRC(Bb, tid);
    const bf16_t* bS1 = CHUNK_SRC(Bb, tid + 256);
    const bf16_t* bS2 = CHUNK_SRC(Bb, tid + 512);
    const bf16_t* bS3 = CHUNK_SRC(Bb, tid + 768);
#undef CHUNK_SRC

    auto stage = [&](int buf, int k0) {
        __builtin_amdgcn_global_load_lds((gvoid*)(aS0 + k0),
            (svoid*)(As[buf] + (size_t)tid * 8), 16, 0, 0);
        __builtin_amdgcn_global_load_lds((gvoid*)(aS1 + k0),
            (svoid*)(As[buf] + (size_t)(tid + 256) * 8), 16, 0, 0);
        __builtin_amdgcn_global_load_lds((gvoid*)(bS0 + k0),
            (svoid*)(Bs[buf] + (size_t)tid * 8), 16, 0, 0);
        __builtin_amdgcn_global_load_lds((gvoid*)(bS1 + k0),
            (svoid*)(Bs[buf] + (size_t)(tid + 256) * 8), 16, 0, 0);
        __builtin_amdgcn_global_load_lds((gvoid*)(bS2 + k0),
            (svoid*)(Bs[buf] + (size_t)(tid + 512) * 8), 16, 0, 0);
        __builtin_amdgcn_global_load_lds((gvoid*)(bS3 + k0),
            (svoid*)(Bs[buf] + (size_t)(tid + 768) * 8), 16, 0, 0);
    };
    auto compute = [&](int buf) {
#pragma unroll
        for (int kk = 0; kk < 2; ++kk) {
            bf16x8 af[TM], bfr[TN];
#pragma unroll
            for (int i = 0; i < TM; ++i) {
                int r = wm + i * 16 + l16;
                af[i] = *(const bf16x8*)&As[buf][r * BK + SWZ8(r, kk * 4 + quad) * 8];
            }
#pragma unroll
            for (int j = 0; j < TN; ++j) {
                int r = wn + j * 16 + l16;
                bfr[j] = *(const bf16x8*)&Bs[buf][r * BK + SWZ8(r, kk * 4 + quad) * 8];
            }
#pragma unroll
            for (int i = 0; i < TM; ++i)
#pragma unroll
                for (int j = 0; j < TN; ++j)
                    acc[i][j] = __builtin_amdgcn_mfma_f32_16x16x32_bf16(
                        af[i], bfr[j], acc[i][j], 0, 0, 0);
        }
    };

    stage(0, kBeg);
    __syncthreads();                       // drains vmcnt(0): buf0 ready
    for (int t = 0; t < nt - 1; ++t) {
        stage((t + 1) & 1, kBeg + (t + 1) * BK);  // overlaps compute below
        compute(t & 1);
        __syncthreads();                   // drain + barrier: next buf ready
    }
    compute((nt - 1) & 1);

#pragma unroll
    for (int i = 0; i < TM; ++i) {
#pragma unroll
        for (int j = 0; j < TN; ++j) {
            int col = colBase + wn + j * 16 + l16;
            float bv = (SPLITK == 1 || blockIdx.z == 0) ? bias[col] : 0.f;
#pragma unroll
            for (int r = 0; r < 4; ++r) {
                int rowg = rowBase + wm + i * 16 + quad * 4 + r;
                float v = acc[i][j][r] + bv;
                if constexpr (SPLITK == 1) {
                    if (RELU) v = v > 0.f ? v : 0.f;
                    if constexpr (sizeof(TC) == 4)
                        C[(size_t)rowg * N + col] = v;
                    else
                        C[(size_t)rowg * N + col] = (bf16_t)v;
                } else {
                    atomicAdd((float*)&C[(size_t)rowg * N + col], v);
                }
            }
        }
    }
}

extern "C" void kernel_launch(void* const* d_in, const int* in_sizes, int n_in,
                              void* d_out, int out_size, void* d_ws, size_t ws_size,
                              hipStream_t stream) {
    const float* x  = (const float*)d_in[0];
    float* W1 = (float*)d_in[1];
    float* b1 = (float*)d_in[2];
    float* W2 = (float*)d_in[3];
    float* b2 = (float*)d_in[4];
    float* W3 = (float*)d_in[5];
    float* b3 = (float*)d_in[6];
    const float* s0 = (const float*)d_in[7];
    const float* s1 = (const float*)d_in[8];
    const float* s2 = (const float*)d_in[9];
    const float* s3 = (const float*)d_in[10];
    const float* s4 = (const float*)d_in[11];
    const float* s5 = (const float*)d_in[12];

    uint8_t* ws = (uint8_t*)d_ws;
    unsigned int* hist = (unsigned int*)(ws + WS_HIST);
    unsigned int* res  = (unsigned int*)(ws + WS_RES);
    unsigned int* cnt  = (unsigned int*)(ws + WS_CNT);
    unsigned long long* cand = (unsigned long long*)(ws + WS_CAND);
    float* OUT = (float*)d_out;

    if (ws_size >= WS_FAST_END) {
        bf16_t* W1b = (bf16_t*)(ws + WS_W1B);
        float*  b1f = (float*)(ws + WS_B1F);
        bf16_t* W2b = (bf16_t*)(ws + WS_W2B);
        float*  b2f = (float*)(ws + WS_B2F);
        bf16_t* W3b = (bf16_t*)(ws + WS_W3B);
        float*  b3f = (float*)(ws + WS_B3F);
        bf16_t* H1  = (bf16_t*)(ws + WS_H1F);
        bf16_t* H2  = (bf16_t*)(ws + WS_H2F);
        // hb scratch (512 x 32KB = 16 MB) in the W2B region: consumed by
        // reduce_hist before mask_apply overwrites it (stream-ordered).
        unsigned int* hb = (unsigned int*)(ws + WS_W2B);
        // xb parked in the H2 region: only read by GEMM1, which completes
        // before GEMM2 starts writing H2 (same stream).
        bf16_t* xb  = (bf16_t*)(ws + WS_H2F);

        hist_kernel<<<HIST_BLOCKS, 256, 0, stream>>>(s0, s1, s2, s3, s4, s5, hb);
        reduce_hist<<<32, 256, 0, stream>>>(hb, hist);
        select_kernel<<<1, 256, 0, stream>>>(hist, res, cnt);
        mask_apply_fast<<<2048, 256, 0, stream>>>(
            s0, s1, s2, s3, s4, s5, W1, b1, W2, b2, W3, b3,
            W1b, b1f, W2b, b2f, W3b, b3f, res, cnt, cand, x, xb, OUT);
        finalize_fast<<<1, 256, 0, stream>>>(res, cnt, cand,
                                             W1b, b1f, W2b, b2f, W3b, b3f);
        gemm2ph<true, 1, bf16_t>
            <<<dim3(32, 16), 256, 0, stream>>>(xb, W1b, b1f, H1, 1024, 4096, 1024);
        gemm2ph<true, 1, bf16_t>
            <<<dim3(32, 16), 256, 0, stream>>>(H1, W2b, b2f, H2, 1024, 4096, 4096);
        gemm2ph<false, 4, float>
            <<<dim3(8, 16, 4), 256, 0, stream>>>(H2, W3b, b3f, OUT, 1024, 1024, 4096);
    } else {
        bf16_t* H1 = (bf16_t*)(ws + WS_H1);
        bf16_t* H2 = (bf16_t*)(ws + WS_H2);
        zero_kernel<<<33, 256, 0, stream>>>((unsigned int*)ws, 8200);
        hist_atomic_kernel<<<1024, 256, 0, stream>>>(s0, s1, s2, s3, s4, s5, hist);
        select_kernel<<<1, 256, 0, stream>>>(hist, res, cnt);
        mask_apply_kernel<<<2048, 256, 0, stream>>>(s0, s1, s2, s3, s4, s5,
                                                    W1, b1, W2, b2, W3, b3,
                                                    res, cnt, cand);
        finalize_kernel<<<1, 256, 0, stream>>>(res, cnt, cand,
                                               W1, b1, W2, b2, W3, b3);
        gemm_bt<64, 128, true, float, float, bf16_t>
            <<<dim3(32, 16), 256, 0, stream>>>(x, W1, b1, H1, 1024, 4096, 1024);
        gemm_bt<64, 128, true, bf16_t, float, bf16_t>
            <<<dim3(32, 16), 256, 0, stream>>>(H1, W2, b2, H2, 1024, 4096, 4096);
        gemm_bt<64, 64, false, bf16_t, float, float>
            <<<dim3(16, 16), 256, 0, stream>>>(H2, W3, b3, OUT, 1024, 1024, 4096);
    }
}